// Round 8
// baseline (351.371 us; speedup 1.0000x reference)
//
#include <hip/hip_runtime.h>
#include <hip/hip_bf16.h>
#include <cstdint>
#include <math.h>

#define S_LEN 2048
#define DM 1024
#define NQKV 1536
#define MROWS 4096   // B * S

typedef __attribute__((ext_vector_type(8))) short short8;
typedef __attribute__((ext_vector_type(4))) short short4v;
typedef __attribute__((ext_vector_type(4))) float f32x4;

// compiler-level memory ordering point (same-wave LDS RAW; HW is in-order)
#define MEMBAR() __asm__ __volatile__("" ::: "memory")

// 0.125 (1/sqrt(64)) * log2(e), folded into Q at RoPE time
#define QFOLD 0.18033688011112042f
// log2(10000)/32
#define L2I 0.41524101186092029f

__device__ __forceinline__ short f2bf(float x) {
  union { float f; uint32_t u; } v; v.f = x;
  uint32_t r = (v.u + 0x7fffu + ((v.u >> 16) & 1u)) >> 16;
  return (short)(uint16_t)r;
}

__device__ __forceinline__ uint32_t pk2(float a, float b) {
  __hip_bfloat162 h = __float22bfloat162_rn(make_float2(a, b));
  union { __hip_bfloat162 h2; uint32_t u; } cv; cv.h2 = h;
  return cv.u;
}

// ---------------- fp32 -> bf16 vectorized convert ----------------
__global__ void f32_to_bf16_vec(const float* __restrict__ in, short* __restrict__ out, int n4) {
  int i = blockIdx.x * blockDim.x + threadIdx.x;
  if (i < n4) {
    float4 v = ((const float4*)in)[i];
    short4 o;
    o.x = f2bf(v.x); o.y = f2bf(v.y); o.z = f2bf(v.z); o.w = f2bf(v.w);
    ((short4*)out)[i] = o;
  }
}

// ---------------- all weight transposes in ONE launch ----------------
// 640 tiles of 64x64: [0,256) Wq->WcatT; [256,320) Wk->WcatT+1024*1024;
// [320,384) Wv->WcatT+1280*1024; [384,640) Wo->WoT. All sources have R=1024 rows.
__global__ __launch_bounds__(256) void transpose_all(const float* __restrict__ Wq,
    const float* __restrict__ Wk, const float* __restrict__ Wv, const float* __restrict__ Wo,
    short* __restrict__ WcatT, short* __restrict__ WoT) {
  __shared__ short T[64 * 72];
  int t = blockIdx.x;
  const float* src; short* dst; int C;
  if (t < 256)      { src = Wq; dst = WcatT;                        C = 1024; }
  else if (t < 320) { t -= 256; src = Wk; dst = WcatT + 1024*1024;  C = 256; }
  else if (t < 384) { t -= 320; src = Wv; dst = WcatT + 1280*1024;  C = 256; }
  else              { t -= 384; src = Wo; dst = WoT;                C = 1024; }
  const int r0 = (t & 15) * 64, c0 = (t >> 4) * 64;
  const int tid = threadIdx.x;
  #pragma unroll
  for (int i = 0; i < 4; ++i) {
    int chunk = tid + i * 256;
    int r = chunk >> 4, cc = (chunk & 15) * 4;
    float4 v = *(const float4*)&src[(size_t)(r0 + r) * C + c0 + cc];
    T[(cc + 0) * 72 + r] = f2bf(v.x);
    T[(cc + 1) * 72 + r] = f2bf(v.y);
    T[(cc + 2) * 72 + r] = f2bf(v.z);
    T[(cc + 3) * 72 + r] = f2bf(v.w);
  }
  __syncthreads();
  #pragma unroll
  for (int i = 0; i < 2; ++i) {
    int chunk = tid + i * 256;
    int rr = chunk >> 3, kk = (chunk & 7) * 8;
    *(uint4*)&dst[(size_t)(c0 + rr) * 1024 + r0 + kk] = *(uint4*)&T[rr * 72 + kk];
  }
}

// ---------------- QKV GEMM with fused RoPE + bf16-pack epilogue ----------------
// C = Xb[4096][1024] * WcatT^T -> cols [0,1024) Q (rope+QFOLD), [1024,1280) K (rope),
// [1280,1536) V (plain). Writes Qb/Kb/Vb bf16 directly; no fp32 C.
#define BM 128
#define BN 128
#define BKT 64

__global__ __launch_bounds__(256) void gemm_qkv_rope(const short* __restrict__ A,
    const short* __restrict__ BT, short* __restrict__ Qb, short* __restrict__ Kb,
    short* __restrict__ Vb) {
  __shared__ short As[BM * BKT];
  __shared__ short Bs[BN * BKT];
  const int tid = threadIdx.x;
  const int wave = tid >> 6, lane = tid & 63;
  const int quad = lane >> 4, l15 = lane & 15;
  const int wm = (wave >> 1) * 64, wn = (wave & 1) * 64;
  const int m0 = blockIdx.y * BM, n0 = blockIdx.x * BN;
  const int K = DM;

  const int sr = wave * 32 + (lane >> 3);
  const int scol = (lane & 7) * 8;

  f32x4 acc[4][4] = {};

  for (int k0 = 0; k0 < K; k0 += BKT) {
    __syncthreads();
    #pragma unroll
    for (int j = 0; j < 4; ++j) {
      const int r = sr + j * 8;
      __builtin_amdgcn_global_load_lds(
          (const __attribute__((address_space(1))) void*)&A[(size_t)(m0 + r) * K + k0 + scol],
          (__attribute__((address_space(3))) void*)&As[(wave * 4 + j) * 512],
          16, 0, 0);
      __builtin_amdgcn_global_load_lds(
          (const __attribute__((address_space(1))) void*)&BT[(size_t)(n0 + r) * K + k0 + scol],
          (__attribute__((address_space(3))) void*)&Bs[(wave * 4 + j) * 512],
          16, 0, 0);
    }
    __syncthreads();
    #pragma unroll
    for (int ks = 0; ks < 2; ++ks) {
      short8 af[4], bfr[4];
      #pragma unroll
      for (int mi = 0; mi < 4; ++mi)
        af[mi] = *(const short8*)&As[(wm + mi*16 + l15)*BKT + ks*32 + quad*8];
      #pragma unroll
      for (int ni = 0; ni < 4; ++ni)
        bfr[ni] = *(const short8*)&Bs[(wn + ni*16 + l15)*BKT + ks*32 + quad*8];
      #pragma unroll
      for (int mi = 0; mi < 4; ++mi)
        #pragma unroll
        for (int ni = 0; ni < 4; ++ni)
          acc[mi][ni] = __builtin_amdgcn_mfma_f32_16x16x32_bf16(af[mi], bfr[ni], acc[mi][ni], 0, 0, 0);
    }
  }

  // epilogue: colbase is wave-uniform, multiple of 64 (one head per wave span)
  const int colbase = n0 + wn;
  // rotation freqs for this lane's two pair-columns j0=l15, j1=16+l15
  const float inv0 = exp2f(-(float)l15 * L2I);
  const float inv1 = exp2f(-(float)(l15 + 16) * L2I);

  if (colbase < 1024) {           // ---- Q: rope * QFOLD ----
    #pragma unroll
    for (int mi = 0; mi < 4; ++mi)
      #pragma unroll
      for (int r = 0; r < 4; ++r) {
        const int row = m0 + wm + mi*16 + quad*4 + r;
        const int s = row & (S_LEN - 1);
        float a0 = (float)s * inv0, a1 = (float)s * inv1;
        float c0 = cosf(a0), s0 = sinf(a0);
        float c1 = cosf(a1), s1 = sinf(a1);
        size_t base = (size_t)row * 1024 + colbase + l15;
        float x1 = acc[mi][0][r], x2 = acc[mi][2][r];
        Qb[base +  0] = f2bf((x1*c0 - x2*s0) * QFOLD);
        Qb[base + 32] = f2bf((x2*c0 + x1*s0) * QFOLD);
        x1 = acc[mi][1][r]; x2 = acc[mi][3][r];
        Qb[base + 16] = f2bf((x1*c1 - x2*s1) * QFOLD);
        Qb[base + 48] = f2bf((x2*c1 + x1*s1) * QFOLD);
      }
  } else if (colbase < 1280) {    // ---- K: rope ----
    const int kcol = colbase - 1024;
    #pragma unroll
    for (int mi = 0; mi < 4; ++mi)
      #pragma unroll
      for (int r = 0; r < 4; ++r) {
        const int row = m0 + wm + mi*16 + quad*4 + r;
        const int s = row & (S_LEN - 1);
        float a0 = (float)s * inv0, a1 = (float)s * inv1;
        float c0 = cosf(a0), s0 = sinf(a0);
        float c1 = cosf(a1), s1 = sinf(a1);
        size_t base = (size_t)row * 256 + kcol + l15;
        float x1 = acc[mi][0][r], x2 = acc[mi][2][r];
        Kb[base +  0] = f2bf(x1*c0 - x2*s0);
        Kb[base + 32] = f2bf(x2*c0 + x1*s0);
        x1 = acc[mi][1][r]; x2 = acc[mi][3][r];
        Kb[base + 16] = f2bf(x1*c1 - x2*s1);
        Kb[base + 48] = f2bf(x2*c1 + x1*s1);
      }
  } else {                        // ---- V: plain bf16 ----
    const int vcol = colbase - 1280;
    #pragma unroll
    for (int mi = 0; mi < 4; ++mi)
      #pragma unroll
      for (int ni = 0; ni < 4; ++ni)
        #pragma unroll
        for (int r = 0; r < 4; ++r) {
          const int row = m0 + wm + mi*16 + quad*4 + r;
          Vb[(size_t)row * 256 + vcol + ni*16 + l15] = f2bf(acc[mi][ni][r]);
        }
  }
}

// ---------------- plain bf16 MFMA GEMM (out-projection), fp32 C ----------------
__global__ __launch_bounds__(256) void gemm_bf16(const short* __restrict__ A,
    const short* __restrict__ BT, float* __restrict__ C, int M, int N, int K) {
  __shared__ short As[BM * BKT];
  __shared__ short Bs[BN * BKT];
  const int tid = threadIdx.x;
  const int wave = tid >> 6, lane = tid & 63;
  const int quad = lane >> 4, l15 = lane & 15;
  const int wm = (wave >> 1) * 64, wn = (wave & 1) * 64;
  const int m0 = blockIdx.y * BM, n0 = blockIdx.x * BN;

  const int sr = wave * 32 + (lane >> 3);
  const int scol = (lane & 7) * 8;

  f32x4 acc[4][4] = {};

  for (int k0 = 0; k0 < K; k0 += BKT) {
    __syncthreads();
    #pragma unroll
    for (int j = 0; j < 4; ++j) {
      const int r = sr + j * 8;
      __builtin_amdgcn_global_load_lds(
          (const __attribute__((address_space(1))) void*)&A[(size_t)(m0 + r) * K + k0 + scol],
          (__attribute__((address_space(3))) void*)&As[(wave * 4 + j) * 512],
          16, 0, 0);
      __builtin_amdgcn_global_load_lds(
          (const __attribute__((address_space(1))) void*)&BT[(size_t)(n0 + r) * K + k0 + scol],
          (__attribute__((address_space(3))) void*)&Bs[(wave * 4 + j) * 512],
          16, 0, 0);
    }
    __syncthreads();
    #pragma unroll
    for (int ks = 0; ks < 2; ++ks) {
      short8 af[4], bfr[4];
      #pragma unroll
      for (int mi = 0; mi < 4; ++mi)
        af[mi] = *(const short8*)&As[(wm + mi*16 + l15)*BKT + ks*32 + quad*8];
      #pragma unroll
      for (int ni = 0; ni < 4; ++ni)
        bfr[ni] = *(const short8*)&Bs[(wn + ni*16 + l15)*BKT + ks*32 + quad*8];
      #pragma unroll
      for (int mi = 0; mi < 4; ++mi)
        #pragma unroll
        for (int ni = 0; ni < 4; ++ni)
          acc[mi][ni] = __builtin_amdgcn_mfma_f32_16x16x32_bf16(af[mi], bfr[ni], acc[mi][ni], 0, 0, 0);
    }
  }
  #pragma unroll
  for (int mi = 0; mi < 4; ++mi)
    #pragma unroll
    for (int ni = 0; ni < 4; ++ni)
      #pragma unroll
      for (int r = 0; r < 4; ++r)
        C[(size_t)(m0 + wm + mi*16 + quad*4 + r)*N + (n0 + wn + ni*16 + l15)] = acc[mi][ni][r];
}

// ---------------- V transpose: Vb[b*S+s][kvh*64+d] -> Vt[(b*4+kvh)*64+d][s] ----------------
__global__ __launch_bounds__(256) void transpose_v(const short* __restrict__ Vb,
                                                   short* __restrict__ Vt) {
  __shared__ short T[64 * 72];
  const int s0 = blockIdx.x * 64;
  const int bh = blockIdx.y;
  const int b = bh >> 2, kvh = bh & 3;
  const int tid = threadIdx.x;
  #pragma unroll
  for (int i = 0; i < 2; ++i) {
    int chunk = tid + i * 256;
    int r = chunk >> 3, c = (chunk & 7) * 8;
    short8 v = *(const short8*)&Vb[(size_t)(b*S_LEN + s0 + r)*256 + kvh*64 + c];
    #pragma unroll
    for (int t = 0; t < 8; ++t) T[(c + t) * 72 + r] = v[t];
  }
  __syncthreads();
  #pragma unroll
  for (int i = 0; i < 2; ++i) {
    int chunk = tid + i * 256;
    int rr = chunk >> 3, kk = (chunk & 7) * 8;
    *(uint4*)&Vt[(size_t)(bh*64 + rr)*S_LEN + s0 + kk] = *(uint4*)&T[rr * 72 + kk];
  }
}

// ---------------- causal GQA flash attention v6 (unchanged, known-good) ----------------
#define PSTR 136

__global__ __launch_bounds__(256, 2) void fattn6(const short* __restrict__ Qb,
    const short* __restrict__ Kb, const short* __restrict__ Vt, short* __restrict__ Ctx) {
  __shared__ short Ks[128 * 72];        // K tile [kv 128][d 64]
  __shared__ short Vts[64 * PSTR];      // V^T tile [d 64][kv 128]
  __shared__ short Ps[4 * 16 * PSTR];   // per-wave P [q 16][kv 128]
  const int idx = blockIdx.x;
  const int pi  = idx & 15;
  const int h   = (idx >> 4) & 15;
  const int b   = idx >> 8;
  const int kvh = h >> 2;
  const int tid = threadIdx.x, wave = tid >> 6, lane = tid & 63;
  const int quad = lane >> 4, l15 = lane & 15;
  const int roff = wave * 16;
  const size_t qbase  = (size_t)b * S_LEN * 1024;
  const size_t kbase  = (size_t)b * S_LEN * 256;
  const size_t vtbase = (size_t)(b*4 + kvh) * 64 * S_LEN;
  short* Psw = Ps + wave * 16 * PSTR;

  for (int half = 0; half < 2; ++half) {
    const int jt = half ? (31 - pi) : pi;
    const int q0 = jt * 64;
    const int ntiles = (jt >> 1) + 1;     // ntiles(i)+ntiles(31-i) == 17
    const int qrow = q0 + roff + l15;

    const short* qp = &Qb[qbase + (size_t)(q0 + roff + l15)*1024 + h*64 + quad*8];
    short8 qf0 = *(const short8*)qp;
    short8 qf1 = *(const short8*)(qp + 32);

    f32x4 O[4] = {};
    float ll = 0.f;

    short8 kreg[4], vreg[4];
    #pragma unroll
    for (int i = 0; i < 4; ++i) {
      int chunk = tid + i * 256;
      int kr = chunk >> 3, kc = (chunk & 7) * 8;
      kreg[i] = *(const short8*)&Kb[kbase + (size_t)kr*256 + kvh*64 + kc];
      int vr = chunk >> 4, vc = (chunk & 15) * 8;
      vreg[i] = *(const short8*)&Vt[vtbase + (size_t)vr*S_LEN + vc];
    }

    for (int t = 0; t < ntiles; ++t) {
      const int k0 = t * 128;
      __syncthreads();
      #pragma unroll
      for (int i = 0; i < 4; ++i) {
        int chunk = tid + i * 256;
        int kr = chunk >> 3, kc = (chunk & 7) * 8;
        *(short8*)&Ks[kr*72 + kc] = kreg[i];
        int vr = chunk >> 4, vc = (chunk & 15) * 8;
        *(short8*)&Vts[vr*PSTR + vc] = vreg[i];
      }
      __syncthreads();
      if (t + 1 < ntiles) {
        const int kn = (t + 1) * 128;
        #pragma unroll
        for (int i = 0; i < 4; ++i) {
          int chunk = tid + i * 256;
          int kr = chunk >> 3, kc = (chunk & 7) * 8;
          kreg[i] = *(const short8*)&Kb[kbase + (size_t)(kn + kr)*256 + kvh*64 + kc];
          int vr = chunk >> 4, vc = (chunk & 15) * 8;
          vreg[i] = *(const short8*)&Vt[vtbase + (size_t)vr*S_LEN + kn + vc];
        }
      }

      f32x4 sc[8];
      #pragma unroll
      for (int nt = 0; nt < 8; ++nt) {
        short8 kf0 = *(const short8*)&Ks[(nt*16 + l15)*72 + quad*8];
        short8 kf1 = *(const short8*)&Ks[(nt*16 + l15)*72 + 32 + quad*8];
        f32x4 a = {0.f, 0.f, 0.f, 0.f};
        a = __builtin_amdgcn_mfma_f32_16x16x32_bf16(kf0, qf0, a, 0, 0, 0);
        a = __builtin_amdgcn_mfma_f32_16x16x32_bf16(kf1, qf1, a, 0, 0, 0);
        sc[nt] = a;
      }
      if (t == ntiles - 1) {
        #pragma unroll
        for (int nt = 0; nt < 8; ++nt)
          #pragma unroll
          for (int r = 0; r < 4; ++r)
            if (k0 + nt*16 + quad*4 + r > qrow) sc[nt][r] = -1e30f;
      }
      #pragma unroll
      for (int nt = 0; nt < 8; ++nt) {
        float p0 = exp2f(sc[nt][0]);
        float p1 = exp2f(sc[nt][1]);
        float p2 = exp2f(sc[nt][2]);
        float p3 = exp2f(sc[nt][3]);
        ll += (p0 + p1) + (p2 + p3);
        union { uint2 uu; short4v s; } pkc;
        pkc.uu.x = pk2(p0, p1); pkc.uu.y = pk2(p2, p3);
        *(short4v*)&Psw[l15*PSTR + nt*16 + quad*4] = pkc.s;
      }
      MEMBAR();
      #pragma unroll
      for (int ks = 0; ks < 4; ++ks) {
        short8 a = *(const short8*)&Psw[l15*PSTR + ks*32 + quad*8];
        #pragma unroll
        for (int d = 0; d < 4; ++d) {
          short8 bv = *(const short8*)&Vts[(d*16 + l15)*PSTR + ks*32 + quad*8];
          O[d] = __builtin_amdgcn_mfma_f32_16x16x32_bf16(a, bv, O[d], 0, 0, 0);
        }
      }
    }

    ll += __shfl_xor(ll, 16, 64);
    ll += __shfl_xor(ll, 32, 64);
    #pragma unroll
    for (int r = 0; r < 4; ++r) {
      float lr = __shfl(ll, quad*4 + r, 64);
      float inv = 1.0f / lr;
      #pragma unroll
      for (int d = 0; d < 4; ++d) {
        int qr = q0 + roff + quad*4 + r;
        Ctx[qbase + (size_t)qr*1024 + h*64 + d*16 + l15] = f2bf(O[d][r] * inv);
      }
    }
  }
}

extern "C" void kernel_launch(void* const* d_in, const int* in_sizes, int n_in,
                              void* d_out, int out_size, void* d_ws, size_t ws_size,
                              hipStream_t stream) {
  const float* x  = (const float*)d_in[0];
  const float* Wq = (const float*)d_in[1];
  const float* Wk = (const float*)d_in[2];
  const float* Wv = (const float*)d_in[3];
  const float* Wo = (const float*)d_in[4];
  float* out = (float*)d_out;

  char* w = (char*)d_ws;
  short* Xb    = (short*)w;  w += (size_t)MROWS * DM * 2;
  short* WcatT = (short*)w;  w += (size_t)NQKV * DM * 2;
  short* WoT   = (short*)w;  w += (size_t)DM * DM * 2;
  short* Qbuf  = (short*)w;  w += (size_t)MROWS * DM * 2;
  short* Kbuf  = (short*)w;  w += (size_t)MROWS * 256 * 2;
  short* Vbuf  = (short*)w;  w += (size_t)MROWS * 256 * 2;
  short* Vt    = (short*)w;  w += (size_t)8 * 64 * S_LEN * 2;
  short* Ctx   = (short*)w;  w += (size_t)MROWS * DM * 2;

  f32_to_bf16_vec<<<dim3(4096), dim3(256), 0, stream>>>(x, Xb, MROWS * DM / 4);
  transpose_all<<<dim3(640), dim3(256), 0, stream>>>(Wq, Wk, Wv, Wo, WcatT, WoT);
  gemm_qkv_rope<<<dim3(NQKV / BN, MROWS / BM), dim3(256), 0, stream>>>(Xb, WcatT, Qbuf, Kbuf, Vbuf);
  transpose_v<<<dim3(32, 8), dim3(256), 0, stream>>>(Vbuf, Vt);
  fattn6<<<dim3(512), dim3(256), 0, stream>>>(Qbuf, Kbuf, Vt, Ctx);
  gemm_bf16<<<dim3(DM / BN, MROWS / BM), dim3(256), 0, stream>>>(Ctx, WoT, out, MROWS, DM, DM);
}